// Round 1
// baseline (295.448 us; speedup 1.0000x reference)
//
#include <hip/hip_runtime.h>
#include <math.h>

typedef __bf16 bf16x8 __attribute__((ext_vector_type(16/2)));
typedef float f32x16 __attribute__((ext_vector_type(16)));

#define NTOK 131072
#define HDIM 128
#define ODIM 128
#define NEXP 8
// K is padded to 9 kt-steps of 16: kt 0..7 = real H, kt 8 = bias row (x side = 1.0)

__device__ __forceinline__ unsigned short f2bf(float f){
  union { float f; unsigned u; } v; v.f = f;
  unsigned r = v.u + 0x7FFFu + ((v.u >> 16) & 1u);
  return (unsigned short)(r >> 16);
}

// ---------------------------------------------------------------------------
// Kernel 1: pack W into A-operand fragment layout (transposed GEMM: A[m=o][k=h])
// pw flat: [e][mt(4)][kt(9)][lane(64)][j(8)] bf16
// A-frag mapping (v_mfma_f32_32x32x16_bf16): A[m=lane&31][k=(lane>>5)*8+j]
// kt==8: k-local 0 row = b_expert[e][o], rest zero.
__global__ void pack_w(const float* __restrict__ we, const float* __restrict__ be,
                       unsigned short* __restrict__ pw){
  int f = blockIdx.x * 256 + threadIdx.x;      // 0..18431, one per (e,mt,kt,l)
  int l  = f & 63;
  int kt = (f >> 6) % 9;
  int emt = f / (64 * 9);
  int mt = emt & 3;
  int e  = emt >> 2;
  int o  = (mt << 5) + (l & 31);
  unsigned short vals[8];
#pragma unroll
  for (int j = 0; j < 8; ++j){
    int kl = ((l >> 5) << 3) + j;              // k within 16-step
    float v;
    if (kt < 8){
      int h = kt * 16 + kl;
      v = we[(e * HDIM + h) * ODIM + o];
    } else {
      v = (kl == 0) ? be[e * ODIM + o] : 0.0f;
    }
    vals[j] = f2bf(v);
  }
  // 16B store
  *(bf16x8*)(pw + (size_t)f * 8) = *(bf16x8*)vals;
}

// ---------------------------------------------------------------------------
// Kernel 2: f32 gating. One thread per token. gates[n][8] dense (2 nonzero).
__global__ void gating(const float* __restrict__ x, const float* __restrict__ wg,
                       float* __restrict__ gates){
  int tok = blockIdx.x * 256 + threadIdx.x;
  const float4* xr = (const float4*)(x + (size_t)tok * HDIM);
  float lg[8];
#pragma unroll
  for (int e = 0; e < 8; ++e) lg[e] = 0.0f;
#pragma unroll 4
  for (int h4 = 0; h4 < 32; ++h4){
    float4 v = xr[h4];
    const float* wr = wg + h4 * 32;            // rows h4*4 .. h4*4+3, each 8 wide
#pragma unroll
    for (int e = 0; e < 8; ++e)
      lg[e] += v.x * wr[e] + v.y * wr[8 + e] + v.z * wr[16 + e] + v.w * wr[24 + e];
  }
  // top-2, ties -> lowest index first (matches lax.top_k)
  int i1 = 0; float v1 = lg[0];
#pragma unroll
  for (int e = 1; e < 8; ++e) if (lg[e] > v1){ v1 = lg[e]; i1 = e; }
  int i2 = -1; float v2 = -3.4e38f;
#pragma unroll
  for (int e = 0; e < 8; ++e) if (e != i1 && lg[e] > v2){ v2 = lg[e]; i2 = e; }
  float ex = __expf(v2 - v1);                  // <= 1
  float inv = 1.0f / (1.0f + ex);
  float g1 = inv, g2 = ex * inv;
  float og[8];
#pragma unroll
  for (int e = 0; e < 8; ++e) og[e] = 0.0f;
  og[i1] = g1; og[i2] = g2;
  float4* gp = (float4*)(gates + (size_t)tok * 8);
  gp[0] = make_float4(og[0], og[1], og[2], og[3]);
  gp[1] = make_float4(og[4], og[5], og[6], og[7]);
}

// ---------------------------------------------------------------------------
// Kernel 3: main MoE FFN. Transposed MFMA: C[o][token] = sum_h W[h][o]*x[t][h].
// Block = 256 thr (4 waves), 128 tokens. Wave: 2 o-tiles(32) x 2 token-groups(32).
// x staged in LDS in B-frag order: xlds[tg(4)][kt(9)][lane(64)][j(8)] bf16.
// B-frag mapping: B[k=(lane>>5)*8+j][n=lane&31] = x[token=tg*32+(lane&31)][h=kt*16+k]
__launch_bounds__(256, 2)
__global__ void moe_main(const float* __restrict__ x, const float* __restrict__ gates,
                         const unsigned short* __restrict__ pw, float* __restrict__ out){
  __shared__ unsigned short xlds[4 * 9 * 64 * 8];   // 36 KiB
  __shared__ float glds[128 * 8];                   //  4 KiB

  int t = threadIdx.x;
  size_t tokbase = (size_t)blockIdx.x * 128;

  // stage gates tile (coalesced)
  {
    const float4* gsrc = (const float4*)(gates + tokbase * 8);
    ((float4*)glds)[t] = gsrc[t];
  }
  // stage bias x-column (kt=8): B[k=0][*]=1.0 -> lane<32, j==0
  {
    int tg = t >> 6, ll = t & 63;
    unsigned long long lo = (ll < 32) ? 0x3F80ull : 0ull;  // bf16 1.0 in elem 0
    unsigned long long* dst = (unsigned long long*)&xlds[(((tg * 9) + 8) * 64 + ll) * 8];
    dst[0] = lo; dst[1] = 0ull;
  }
  // stage x tile -> bf16 frag layout. Pass p: lanes0-31 of each wave read one
  // token's contiguous 512B (coalesced).
  {
    const float4* xs = (const float4*)(x + tokbase * HDIM);
#pragma unroll 4
    for (int p = 0; p < 16; ++p){
      int token = p * 8 + (t >> 5);
      int hq = t & 31;
      float4 v = xs[token * 32 + hq];
      int h = hq * 4;
      int tg = token >> 5, slot = token & 31;
      int kt = h >> 4, kk = h & 15;
      int l = slot + ((kk >> 3) << 5);
      int j0 = kk & 7;
      unsigned long long pk = (unsigned long long)f2bf(v.x)
                            | ((unsigned long long)f2bf(v.y) << 16)
                            | ((unsigned long long)f2bf(v.z) << 32)
                            | ((unsigned long long)f2bf(v.w) << 48);
      *(unsigned long long*)&xlds[((((tg * 9) + kt) * 64 + l) * 8) + j0] = pk;
    }
  }
  __syncthreads();

  int w = t >> 6, l = t & 63;
  int l32 = l & 31, lh = l >> 5;
  int mtb = (w & 1) * 2;          // o-tile base
  int tgb = (w >> 1) * 2;         // token-group base

  // x B-frags: reused across all 8 experts (72 VGPRs)
  bf16x8 xb[2][9];
#pragma unroll
  for (int ti = 0; ti < 2; ++ti)
#pragma unroll
    for (int kt = 0; kt < 9; ++kt)
      xb[ti][kt] = *(const bf16x8*)&xlds[((((tgb + ti) * 9) + kt) * 64 + l) * 8];

  // gate regs: g[ti][e] for this lane's token (lane-uniform across C regs)
  float g[2][8];
#pragma unroll
  for (int ti = 0; ti < 2; ++ti){
    const float4* gp = (const float4*)&glds[(((tgb + ti) * 32) + l32) * 8];
    float4 a = gp[0], b = gp[1];
    g[ti][0] = a.x; g[ti][1] = a.y; g[ti][2] = a.z; g[ti][3] = a.w;
    g[ti][4] = b.x; g[ti][5] = b.y; g[ti][6] = b.z; g[ti][7] = b.w;
  }

  f32x16 zero16;
#pragma unroll
  for (int i = 0; i < 16; ++i) zero16[i] = 0.0f;
  f32x16 tot[2][2];
#pragma unroll
  for (int mi = 0; mi < 2; ++mi)
#pragma unroll
    for (int ti = 0; ti < 2; ++ti) tot[mi][ti] = zero16;

  const bf16x8* pwp = (const bf16x8*)pw;
#pragma unroll 1
  for (int e = 0; e < 8; ++e){
#pragma unroll 1
    for (int mi = 0; mi < 2; ++mi){
      int mt = mtb + mi;
      const bf16x8* ap = pwp + ((size_t)(e * 4 + mt) * 9) * 64 + l;
      bf16x8 aw[9];
#pragma unroll
      for (int kt = 0; kt < 9; ++kt) aw[kt] = ap[kt * 64];
#pragma unroll
      for (int ti = 0; ti < 2; ++ti){
        f32x16 p = __builtin_amdgcn_mfma_f32_32x32x16_bf16(aw[0], xb[ti][0], zero16, 0, 0, 0);
#pragma unroll
        for (int kt = 1; kt < 9; ++kt)
          p = __builtin_amdgcn_mfma_f32_32x32x16_bf16(aw[kt], xb[ti][kt], p, 0, 0, 0);
        float ge = g[ti][e];
#pragma unroll
        for (int r = 0; r < 16; ++r) tot[mi][ti][r] += ge * p[r];
      }
    }
  }

  // store: C[o][token] -> out[token][o]; regs rg*4..rg*4+3 are 4 consecutive o.
#pragma unroll
  for (int mi = 0; mi < 2; ++mi){
    int mt = mtb + mi;
#pragma unroll
    for (int ti = 0; ti < 2; ++ti){
      size_t token = tokbase + (size_t)(tgb + ti) * 32 + l32;
      float* orow = out + token * ODIM;
#pragma unroll
      for (int rg = 0; rg < 4; ++rg){
        int ob = mt * 32 + rg * 8 + lh * 4;
        float4 st = make_float4(tot[mi][ti][rg * 4 + 0], tot[mi][ti][rg * 4 + 1],
                                tot[mi][ti][rg * 4 + 2], tot[mi][ti][rg * 4 + 3]);
        *(float4*)(orow + ob) = st;
      }
    }
  }
}

// ---------------------------------------------------------------------------
extern "C" void kernel_launch(void* const* d_in, const int* in_sizes, int n_in,
                              void* d_out, int out_size, void* d_ws, size_t ws_size,
                              hipStream_t stream){
  const float* x  = (const float*)d_in[0];
  const float* wg = (const float*)d_in[1];
  // d_in[2] = w_noise (inactive in eval mode)
  const float* we = (const float*)d_in[3];
  const float* be = (const float*)d_in[4];
  // d_in[5] = top_k (== 2, baked into gating kernel)
  float* out = (float*)d_out;

  unsigned short* pw = (unsigned short*)d_ws;              // 294,912 B
  float* gates = (float*)((char*)d_ws + 294912);           // 4 MiB

  pack_w  <<<72,   256, 0, stream>>>(we, be, pw);
  gating  <<<512,  256, 0, stream>>>(x, wg, gates);
  moe_main<<<1024, 256, 0, stream>>>(x, gates, pw, out);
}

// Round 2
// 289.940 us; speedup vs baseline: 1.0190x; 1.0190x over previous
//
#include <hip/hip_runtime.h>
#include <math.h>

typedef __bf16 bf16x8 __attribute__((ext_vector_type(8)));
typedef float f32x16 __attribute__((ext_vector_type(16)));

#define NTOK 131072
#define HDIM 128
#define ODIM 128
#define NEXP 8
// K padded to 9 kt-steps of 16: kt 0..7 = real H, kt 8 = bias row (x side = 1.0)

__device__ __forceinline__ unsigned short f2bf(float f){
  union { float f; unsigned u; } v; v.f = f;
  unsigned r = v.u + 0x7FFFu + ((v.u >> 16) & 1u);
  return (unsigned short)(r >> 16);
}

// ---------------------------------------------------------------------------
// Kernel 1: pack W into A-operand fragment layout (transposed GEMM: A[m=o][k=h])
// pw flat: [e][mt(4)][kt(9)][lane(64)][j(8)] bf16
// A-frag mapping (v_mfma_f32_32x32x16_bf16): A[m=lane&31][k=(lane>>5)*8+j]
// kt==8: k-local 0 row = b_expert[e][o], rest zero.
__global__ void pack_w(const float* __restrict__ we, const float* __restrict__ be,
                       unsigned short* __restrict__ pw){
  int f = blockIdx.x * 256 + threadIdx.x;      // 0..18431, one per (e,mt,kt,l)
  int l  = f & 63;
  int kt = (f >> 6) % 9;
  int emt = f / (64 * 9);
  int mt = emt & 3;
  int e  = emt >> 2;
  int o  = (mt << 5) + (l & 31);
  unsigned short vals[8];
#pragma unroll
  for (int j = 0; j < 8; ++j){
    int kl = ((l >> 5) << 3) + j;              // k within 16-step
    float v;
    if (kt < 8){
      int h = kt * 16 + kl;
      v = we[(e * HDIM + h) * ODIM + o];
    } else {
      v = (kl == 0) ? be[e * ODIM + o] : 0.0f;
    }
    vals[j] = f2bf(v);
  }
  *(bf16x8*)(pw + (size_t)f * 8) = *(bf16x8*)vals;
}

// ---------------------------------------------------------------------------
// Kernel 2: f32 gating, LDS-staged for coalescing. 64 tokens/block, 256 thr.
// All threads stage x rows coalesced into LDS (stride 132 pad); threads 0..63
// each compute one token's 8 logits + top-2 softmax from LDS.
__global__ void gating(const float* __restrict__ x, const float* __restrict__ wg,
                       float* __restrict__ gates){
  __shared__ float xs[64 * 132];    // 33.8 KiB, row stride 132 (16B-aligned, pad 4)
  __shared__ float wgl[128 * 8];    // 4 KiB, [h][e]
  int t = threadIdx.x;
  size_t tokbase = (size_t)blockIdx.x * 64;

  ((float4*)wgl)[t] = ((const float4*)wg)[t];            // 1024 floats = 256 f4

  const float4* xsrc = (const float4*)(x + tokbase * HDIM);
#pragma unroll
  for (int i = 0; i < 8; ++i){
    int idx = i * 256 + t;          // float4 id, 0..2047
    int tok = idx >> 5, c = idx & 31;
    *(float4*)&xs[tok * 132 + c * 4] = xsrc[idx];
  }
  __syncthreads();

  if (t < 64){
    float lg[8];
#pragma unroll
    for (int e = 0; e < 8; ++e) lg[e] = 0.0f;
#pragma unroll 8
    for (int c = 0; c < 32; ++c){
      float4 v = *(float4*)&xs[t * 132 + c * 4];
      const float* wr = wgl + c * 32;
#pragma unroll
      for (int e = 0; e < 8; ++e)
        lg[e] += v.x * wr[e] + v.y * wr[8 + e] + v.z * wr[16 + e] + v.w * wr[24 + e];
    }
    // top-2, ties -> lowest index first (matches lax.top_k)
    int i1 = 0; float v1 = lg[0];
#pragma unroll
    for (int e = 1; e < 8; ++e) if (lg[e] > v1){ v1 = lg[e]; i1 = e; }
    int i2 = -1; float v2 = -3.4e38f;
#pragma unroll
    for (int e = 0; e < 8; ++e) if (e != i1 && lg[e] > v2){ v2 = lg[e]; i2 = e; }
    float ex = __expf(v2 - v1);
    float inv = 1.0f / (1.0f + ex);
    float og[8];
#pragma unroll
    for (int e = 0; e < 8; ++e) og[e] = 0.0f;
    og[i1] = inv; og[i2] = ex * inv;
    float4* gp = (float4*)(gates + (tokbase + t) * 8);
    gp[0] = make_float4(og[0], og[1], og[2], og[3]);
    gp[1] = make_float4(og[4], og[5], og[6], og[7]);
  }
}

// ---------------------------------------------------------------------------
// Kernel 3: main MoE FFN. Transposed MFMA: C[o][token] = sum_h W[h][o]*x[t][h].
// Gate is lane-uniform in this orientation (token = lane&31) -> 1 fmac/reg.
// Epilogue: LDS transpose (2 x 64-token phases, XOR-swizzled, conflict-free)
// -> fully coalesced out stores (fixes 9.2x write amplification of R1).
__launch_bounds__(256, 2)
__global__ void moe_main(const float* __restrict__ x, const float* __restrict__ gates,
                         const unsigned short* __restrict__ pw, float* __restrict__ out){
  __shared__ unsigned short xlds[4 * 9 * 64 * 8];   // 36 KiB (reused as f32 transpose buf)
  __shared__ float glds[128 * 8];                   //  4 KiB

  int t = threadIdx.x;
  size_t tokbase = (size_t)blockIdx.x * 128;

  // stage gates tile (coalesced)
  {
    const float4* gsrc = (const float4*)(gates + tokbase * 8);
    ((float4*)glds)[t] = gsrc[t];
  }
  // stage bias x-column (kt=8): B[k=0][*]=1.0 -> lane<32, j==0
  {
    int tg = t >> 6, ll = t & 63;
    unsigned long long lo = (ll < 32) ? 0x3F80ull : 0ull;  // bf16 1.0 in elem 0
    unsigned long long* dst = (unsigned long long*)&xlds[(((tg * 9) + 8) * 64 + ll) * 8];
    dst[0] = lo; dst[1] = 0ull;
  }
  // stage x tile -> bf16 B-frag layout (coalesced reads: 32 lanes per token row)
  {
    const float4* xs = (const float4*)(x + tokbase * HDIM);
#pragma unroll 4
    for (int p = 0; p < 16; ++p){
      int token = p * 8 + (t >> 5);
      int hq = t & 31;
      float4 v = xs[token * 32 + hq];
      int h = hq * 4;
      int tg = token >> 5, slot = token & 31;
      int kt = h >> 4, kk = h & 15;
      int l = slot + ((kk >> 3) << 5);
      int j0 = kk & 7;
      unsigned long long pk = (unsigned long long)f2bf(v.x)
                            | ((unsigned long long)f2bf(v.y) << 16)
                            | ((unsigned long long)f2bf(v.z) << 32)
                            | ((unsigned long long)f2bf(v.w) << 48);
      *(unsigned long long*)&xlds[((((tg * 9) + kt) * 64 + l) * 8) + j0] = pk;
    }
  }
  __syncthreads();

  int w = t >> 6, l = t & 63;
  int l32 = l & 31, lh = l >> 5;
  int mtb = (w & 1) * 2;          // o-tile base
  int tgb = (w >> 1) * 2;         // token-group base

  // x B-frags: reused across all 8 experts
  bf16x8 xb[2][9];
#pragma unroll
  for (int ti = 0; ti < 2; ++ti)
#pragma unroll
    for (int kt = 0; kt < 9; ++kt)
      xb[ti][kt] = *(const bf16x8*)&xlds[((((tgb + ti) * 9) + kt) * 64 + l) * 8];

  // gate regs: lane-uniform across C regs (token = lane&31)
  float g[2][8];
#pragma unroll
  for (int ti = 0; ti < 2; ++ti){
    const float4* gp = (const float4*)&glds[(((tgb + ti) * 32) + l32) * 8];
    float4 a = gp[0], b = gp[1];
    g[ti][0] = a.x; g[ti][1] = a.y; g[ti][2] = a.z; g[ti][3] = a.w;
    g[ti][4] = b.x; g[ti][5] = b.y; g[ti][6] = b.z; g[ti][7] = b.w;
  }

  f32x16 zero16;
#pragma unroll
  for (int i = 0; i < 16; ++i) zero16[i] = 0.0f;
  f32x16 tot[2][2];
#pragma unroll
  for (int mi = 0; mi < 2; ++mi)
#pragma unroll
    for (int ti = 0; ti < 2; ++ti) tot[mi][ti] = zero16;

  const bf16x8* pwp = (const bf16x8*)pw;
#pragma unroll 1
  for (int e = 0; e < 8; ++e){
#pragma unroll 1
    for (int mi = 0; mi < 2; ++mi){
      int mt = mtb + mi;
      const bf16x8* ap = pwp + ((size_t)(e * 4 + mt) * 9) * 64 + l;
      bf16x8 aw[9];
#pragma unroll
      for (int kt = 0; kt < 9; ++kt) aw[kt] = ap[kt * 64];
#pragma unroll
      for (int ti = 0; ti < 2; ++ti){
        f32x16 p = __builtin_amdgcn_mfma_f32_32x32x16_bf16(aw[0], xb[ti][0], zero16, 0, 0, 0);
#pragma unroll
        for (int kt = 1; kt < 9; ++kt)
          p = __builtin_amdgcn_mfma_f32_32x32x16_bf16(aw[kt], xb[ti][kt], p, 0, 0, 0);
        float ge = g[ti][e];
#pragma unroll
        for (int r = 0; r < 16; ++r) tot[mi][ti][r] += ge * p[r];
      }
    }
  }

  // --- Epilogue: LDS transpose -> coalesced stores ---
  // tb[trow(64)][chunk(32) f4, XOR-swizzled]: 32 KiB, overlaid on dead xlds.
  float* tb = (float*)xlds;
  int myphase = w >> 1;                 // waves 0,1 own tokens 0..63; 2,3 own 64..127
#pragma unroll 1
  for (int ph = 0; ph < 2; ++ph){
    __syncthreads();
    if (myphase == ph){
#pragma unroll
      for (int mi = 0; mi < 2; ++mi){
        int mt = mtb + mi;
#pragma unroll
        for (int ti = 0; ti < 2; ++ti){
          int trow = ti * 32 + l32;     // 0..63
#pragma unroll
          for (int rg = 0; rg < 4; ++rg){
            int o = mt * 32 + rg * 8 + lh * 4;
            int cs = (o >> 2) ^ l32;    // swizzled f4 chunk
            float4 st = make_float4(tot[mi][ti][rg * 4 + 0], tot[mi][ti][rg * 4 + 1],
                                    tot[mi][ti][rg * 4 + 2], tot[mi][ti][rg * 4 + 3]);
            *(float4*)&tb[trow * 128 + cs * 4] = st;
          }
        }
      }
    }
    __syncthreads();
#pragma unroll
    for (int i = 0; i < 8; ++i){
      int idx = i * 256 + t;            // f4 id, 0..2047
      int trow = idx >> 5, c = idx & 31;
      int cs = c ^ (trow & 31);
      float4 v = *(float4*)&tb[trow * 128 + cs * 4];
      *(float4*)(out + (tokbase + (size_t)ph * 64 + trow) * ODIM + c * 4) = v;
    }
  }
}

// ---------------------------------------------------------------------------
extern "C" void kernel_launch(void* const* d_in, const int* in_sizes, int n_in,
                              void* d_out, int out_size, void* d_ws, size_t ws_size,
                              hipStream_t stream){
  const float* x  = (const float*)d_in[0];
  const float* wg = (const float*)d_in[1];
  // d_in[2] = w_noise (inactive in eval mode)
  const float* we = (const float*)d_in[3];
  const float* be = (const float*)d_in[4];
  // d_in[5] = top_k (== 2, baked in)
  float* out = (float*)d_out;

  unsigned short* pw = (unsigned short*)d_ws;              // 294,912 B
  float* gates = (float*)((char*)d_ws + 294912);           // 4 MiB

  pack_w  <<<72,   256, 0, stream>>>(we, be, pw);
  gating  <<<2048, 256, 0, stream>>>(x, wg, gates);
  moe_main<<<1024, 256, 0, stream>>>(x, gates, pw, out);
}